// Round 1
// baseline (1027.105 us; speedup 1.0000x reference)
//
#include <hip/hip_runtime.h>

#define D 64
#define LN_EPS 1e-5f
#define DIV_EPS 1e-6f

// Sum across all 64 lanes of the wave (butterfly). All lanes get the result.
__device__ __forceinline__ float wave_sum(float v) {
#pragma unroll
  for (int m = 1; m < 64; m <<= 1) v += __shfl_xor(v, m, 64);
  return v;
}

// Broadcast lane k's value to all lanes (k is a compile-time constant after
// unroll -> v_readlane_b32 to SGPR, then FMA uses the SGPR operand).
__device__ __forceinline__ float bcast(float v, int k) {
  return __int_as_float(__builtin_amdgcn_readlane(__float_as_int(v), k));
}

// out1 = h@W1 + b1 ; out2 = h@W2 + b2   (one wave per node row; lane = out chan)
// Weight columns live in VGPRs (w1[k] = W1[k][lane]); the h row is broadcast
// per-k via readlane, keeping the inner loop entirely on the VALU pipe.
__global__ __launch_bounds__(256) void node_proj_kernel(
    const float* __restrict__ h,
    const float* __restrict__ W1, const float* __restrict__ b1,
    const float* __restrict__ W2, const float* __restrict__ b2,
    float* __restrict__ out1, float* __restrict__ out2, int n) {
  const int lane = threadIdx.x & 63;
  const int wave = blockIdx.x * 4 + (threadIdx.x >> 6);
  const int nw = gridDim.x * 4;
  float w1[D], w2[D];
#pragma unroll
  for (int k = 0; k < D; ++k) { w1[k] = W1[k * D + lane]; w2[k] = W2[k * D + lane]; }
  const float bb1 = b1[lane], bb2 = b2[lane];
  for (int n0 = wave; n0 < n; n0 += nw) {
    const long base = (long)n0 * D;
    const float hl = h[base + lane];
    float a1 = bb1, a2 = bb2;
#pragma unroll
    for (int k = 0; k < D; ++k) {
      const float s = bcast(hl, k);
      a1 = fmaf(s, w1[k], a1);
      a2 = fmaf(s, w2[k], a2);
    }
    out1[base + lane] = a1;
    out2[base + lane] = a2;
  }
}

// Per edge (one wave per edge):
//   t = B1h[src] + B2h[dst] + (e_row @ B3w + B3b)
//   e_out = relu(LN(t)) + e_row            -> written to output
//   sig = sigmoid(e_out)
//   atomic: ssh[dst] += A2h[src]*sig ; ss[dst] += sig
__global__ __launch_bounds__(256) void edge_kernel(
    const float* __restrict__ e, const int* __restrict__ src,
    const int* __restrict__ dst,
    const float* __restrict__ B1h, const float* __restrict__ B2h,
    const float* __restrict__ A2h,
    const float* __restrict__ B3w, const float* __restrict__ B3b,
    const float* __restrict__ g, const float* __restrict__ bta,
    float* __restrict__ eout, float* __restrict__ ssh, float* __restrict__ ss,
    int E) {
  const int lane = threadIdx.x & 63;
  const int wave = blockIdx.x * 4 + (threadIdx.x >> 6);
  const int nw = gridDim.x * 4;
  float w3[D];
#pragma unroll
  for (int k = 0; k < D; ++k) w3[k] = B3w[k * D + lane];
  const float bb = B3b[lane], gl = g[lane], bl = bta[lane];
  for (int e0 = wave; e0 < E; e0 += nw) {
    const long base = (long)e0 * D;
    const float el = e[base + lane];
    const int sN = src[e0], dN = dst[e0];
    const float b1v = B1h[(long)sN * D + lane];
    const float b2v = B2h[(long)dN * D + lane];
    const float a2v = A2h[(long)sN * D + lane];
    float acc = bb;
#pragma unroll
    for (int k = 0; k < D; ++k) acc = fmaf(bcast(el, k), w3[k], acc);
    const float x = b1v + b2v + acc;
    const float mu = wave_sum(x) * (1.f / 64.f);
    const float dx = x - mu;
    const float var = wave_sum(dx * dx) * (1.f / 64.f);
    float y = dx * rsqrtf(var + LN_EPS) * gl + bl;
    y = fmaxf(y, 0.f) + el;  // relu + residual
    eout[base + lane] = y;
    const float sg = 1.f / (1.f + __expf(-y));
    atomicAdd(&ssh[(long)dN * D + lane], a2v * sg);
    atomicAdd(&ss[(long)dN * D + lane], sg);
  }
}

// h_out = relu(LN(A1h + ssh/(ss+eps))) + h   (one wave per node row)
__global__ __launch_bounds__(256) void node_out_kernel(
    const float* __restrict__ h, const float* __restrict__ A1h,
    const float* __restrict__ ssh, const float* __restrict__ ss,
    const float* __restrict__ g, const float* __restrict__ bta,
    float* __restrict__ hout, int n) {
  const int lane = threadIdx.x & 63;
  const int wave = blockIdx.x * 4 + (threadIdx.x >> 6);
  const int nw = gridDim.x * 4;
  const float gl = g[lane], bl = bta[lane];
  for (int n0 = wave; n0 < n; n0 += nw) {
    const long base = (long)n0 * D;
    const float x =
        A1h[base + lane] + ssh[base + lane] / (ss[base + lane] + DIV_EPS);
    const float mu = wave_sum(x) * (1.f / 64.f);
    const float dx = x - mu;
    const float var = wave_sum(dx * dx) * (1.f / 64.f);
    float y = dx * rsqrtf(var + LN_EPS) * gl + bl;
    y = fmaxf(y, 0.f) + h[base + lane];
    hout[base + lane] = y;
  }
}

extern "C" void kernel_launch(void* const* d_in, const int* in_sizes, int n_in,
                              void* d_out, int out_size, void* d_ws,
                              size_t ws_size, hipStream_t stream) {
  const float* h = (const float*)d_in[0];
  const float* e = (const float*)d_in[1];
  const int* src = (const int*)d_in[2];
  const int* dst = (const int*)d_in[3];
  const float* A1w = (const float*)d_in[4];
  const float* A1b = (const float*)d_in[5];
  const float* A2w = (const float*)d_in[6];
  const float* A2b = (const float*)d_in[7];
  const float* B1w = (const float*)d_in[8];
  const float* B1b = (const float*)d_in[9];
  const float* B2w = (const float*)d_in[10];
  const float* B2b = (const float*)d_in[11];
  const float* B3w = (const float*)d_in[12];
  const float* B3b = (const float*)d_in[13];
  const float* ln_e_g = (const float*)d_in[14];
  const float* ln_e_b = (const float*)d_in[15];
  const float* ln_h_g = (const float*)d_in[16];
  const float* ln_h_b = (const float*)d_in[17];

  const int N = in_sizes[0] / D;  // 100000
  const int E = in_sizes[1] / D;  // 1000000

  // Workspace layout (f32): A1h, A2h, B1h, B2h, ssh, ss  -> 6*N*D floats
  float* ws = (float*)d_ws;
  float* A1h = ws;
  float* A2h = ws + (size_t)N * D;
  float* B1h = ws + 2 * (size_t)N * D;
  float* B2h = ws + 3 * (size_t)N * D;
  float* ssh = ws + 4 * (size_t)N * D;
  float* ss = ws + 5 * (size_t)N * D;

  // Output: h_out [N*D] then e_ji [E*D], concatenated flat.
  float* hout = (float*)d_out;
  float* eout = (float*)d_out + (size_t)N * D;

  // ws is poisoned 0xAA before every timed call -> zero the accumulators.
  hipMemsetAsync(ssh, 0, 2 * (size_t)N * D * sizeof(float), stream);

  node_proj_kernel<<<1024, 256, 0, stream>>>(h, A1w, A1b, A2w, A2b, A1h, A2h, N);
  node_proj_kernel<<<1024, 256, 0, stream>>>(h, B1w, B1b, B2w, B2b, B1h, B2h, N);
  edge_kernel<<<4096, 256, 0, stream>>>(e, src, dst, B1h, B2h, A2h, B3w, B3b,
                                        ln_e_g, ln_e_b, eout, ssh, ss, E);
  node_out_kernel<<<1024, 256, 0, stream>>>(h, A1h, ssh, ss, ln_h_g, ln_h_b,
                                            hout, N);
}

// Round 3
// 934.939 us; speedup vs baseline: 1.0986x; 1.0986x over previous
//
#include <hip/hip_runtime.h>

#define D 64
#define LN_EPS 1e-5f
#define DIV_EPS 1e-6f

typedef __attribute__((ext_vector_type(8))) short bf16x8;
typedef __attribute__((ext_vector_type(4))) float f32x4;

// f32 -> bf16 round-to-nearest-even
__device__ __forceinline__ short f2bf(float f) {
  unsigned u = __float_as_uint(f);
  unsigned r = (u + 0x7fffu + ((u >> 16) & 1u)) >> 16;
  return (short)r;
}

__device__ __forceinline__ float wave_sum(float v) {
#pragma unroll
  for (int m = 1; m < 64; m <<= 1) v += __shfl_xor(v, m, 64);
  return v;
}

// B-fragment for mfma_f32_16x16x32_bf16 from row-major W[64][64] ([k][c]).
// Lane holds B[k = s*32 + (lane>>4)*8 + j][c = n0*16 + (lane&15)], j=0..7.
__device__ __forceinline__ bf16x8 load_bfrag(const float* __restrict__ W,
                                             int s, int n0, int lane) {
  const int c = n0 * 16 + (lane & 15);
  const int k0 = s * 32 + ((lane >> 4) << 3);
  bf16x8 b;
#pragma unroll
  for (int j = 0; j < 8; ++j) b[j] = f2bf(W[(k0 + j) * D + c]);
  return b;
}

// A-fragments (2 k-steps) for 16 consecutive rows of X starting at r0.
__device__ __forceinline__ void load_afrags(const float* __restrict__ X,
                                            size_t r0, int lane, bf16x8& a0,
                                            bf16x8& a1) {
  const int q = lane >> 4, m = lane & 15;
  const float* rb = X + (r0 + m) * D;
  const float4* p0 = (const float4*)(rb + q * 8);
  const float4* p1 = (const float4*)(rb + 32 + q * 8);
  float4 v0 = p0[0], v1 = p0[1], v2 = p1[0], v3 = p1[1];
  a0 = (bf16x8){f2bf(v0.x), f2bf(v0.y), f2bf(v0.z), f2bf(v0.w),
                f2bf(v1.x), f2bf(v1.y), f2bf(v1.z), f2bf(v1.w)};
  a1 = (bf16x8){f2bf(v2.x), f2bf(v2.y), f2bf(v2.z), f2bf(v2.w),
                f2bf(v3.x), f2bf(v3.y), f2bf(v3.z), f2bf(v3.w)};
}

// Fused node projections: o{0..3} = h @ W{0..3} + b{0..3}. One wave = 16 rows.
__global__ __launch_bounds__(256, 1) void node_proj_mfma(
    const float* __restrict__ h, const float* __restrict__ W0,
    const float* __restrict__ Bb0, const float* __restrict__ W1,
    const float* __restrict__ Bb1, const float* __restrict__ W2,
    const float* __restrict__ Bb2, const float* __restrict__ W3,
    const float* __restrict__ Bb3, float* __restrict__ o0,
    float* __restrict__ o1, float* __restrict__ o2, float* __restrict__ o3,
    int N) {
  const int lane = threadIdx.x & 63;
  const int q = lane >> 4, m = lane & 15;
  const int wave = blockIdx.x * 4 + (threadIdx.x >> 6);
  const int nw = gridDim.x * 4;
  const float* Ws[4] = {W0, W1, W2, W3};
  const float* Bs[4] = {Bb0, Bb1, Bb2, Bb3};
  float* Os[4] = {o0, o1, o2, o3};
  bf16x8 bf[4][2][4];
  float bias[4][4];
#pragma unroll
  for (int mat = 0; mat < 4; ++mat) {
#pragma unroll
    for (int s = 0; s < 2; ++s)
#pragma unroll
      for (int n0 = 0; n0 < 4; ++n0)
        bf[mat][s][n0] = load_bfrag(Ws[mat], s, n0, lane);
#pragma unroll
    for (int n0 = 0; n0 < 4; ++n0) bias[mat][n0] = Bs[mat][n0 * 16 + m];
  }
  for (int r0 = wave * 16; r0 < N; r0 += nw * 16) {
    bf16x8 a0, a1;
    load_afrags(h, (size_t)r0, lane, a0, a1);
#pragma unroll
    for (int mat = 0; mat < 4; ++mat) {
      f32x4 acc[4];
#pragma unroll
      for (int n0 = 0; n0 < 4; ++n0) {
        acc[n0] = (f32x4){0.f, 0.f, 0.f, 0.f};
        acc[n0] = __builtin_amdgcn_mfma_f32_16x16x32_bf16(a0, bf[mat][0][n0],
                                                          acc[n0], 0, 0, 0);
        acc[n0] = __builtin_amdgcn_mfma_f32_16x16x32_bf16(a1, bf[mat][1][n0],
                                                          acc[n0], 0, 0, 0);
      }
      float* Om = Os[mat];
#pragma unroll
      for (int n0 = 0; n0 < 4; ++n0)
#pragma unroll
        for (int r = 0; r < 4; ++r)
          Om[(size_t)(r0 + q * 4 + r) * D + n0 * 16 + m] =
              acc[n0][r] + bias[mat][n0];
    }
  }
}

// Edge pipeline. Phase 1: MFMA GEMV (e@B3w) for this wave's 16 edges, raw acc
// scattered to LDS in row-major. Phase 2: verbatim round-1 logic — one edge at
// a time, lane = channel: gather, butterfly LN, residual, sigmoid, atomics.
__global__ __launch_bounds__(256, 3) void edge_mfma2(
    const float* __restrict__ e, const int* __restrict__ src,
    const int* __restrict__ dst, const float* __restrict__ B1h,
    const float* __restrict__ B2h, const float* __restrict__ A2h,
    const float* __restrict__ W3, const float* __restrict__ B3b,
    const float* __restrict__ g, const float* __restrict__ bta,
    float* __restrict__ eout, float* __restrict__ ssh, float* __restrict__ ss,
    int E) {
  __shared__ float xs[64][65];  // 4 waves x 16 edges x 64 ch (+1 pad)
  const int lane = threadIdx.x & 63;
  const int q = lane >> 4, m = lane & 15;
  const int wid = threadIdx.x >> 6;
  const int gw = blockIdx.x * 4 + wid;
  const int nw = gridDim.x * 4;
  bf16x8 bf[2][4];
#pragma unroll
  for (int s = 0; s < 2; ++s)
#pragma unroll
    for (int n0 = 0; n0 < 4; ++n0) bf[s][n0] = load_bfrag(W3, s, n0, lane);
  const float bb = B3b[lane], gl = g[lane], bl = bta[lane];
  for (int e0 = gw * 16; e0 < E; e0 += nw * 16) {
    // ---- phase 1: MFMA for edges e0..e0+15 ----
    bf16x8 a0, a1;
    load_afrags(e, (size_t)e0, lane, a0, a1);
    f32x4 acc[4];
#pragma unroll
    for (int n0 = 0; n0 < 4; ++n0) {
      acc[n0] = (f32x4){0.f, 0.f, 0.f, 0.f};
      acc[n0] =
          __builtin_amdgcn_mfma_f32_16x16x32_bf16(a0, bf[0][n0], acc[n0], 0, 0, 0);
      acc[n0] =
          __builtin_amdgcn_mfma_f32_16x16x32_bf16(a1, bf[1][n0], acc[n0], 0, 0, 0);
    }
    // C-layout claim: value acc[n0][r] is (row q*4+r, col n0*16+m).
    // Scatter to this wave's private LDS tile (own-wave read-back, no barrier).
#pragma unroll
    for (int n0 = 0; n0 < 4; ++n0)
#pragma unroll
      for (int r = 0; r < 4; ++r)
        xs[(wid << 4) + (q << 2) + r][(n0 << 4) + m] = acc[n0][r];
    // ---- phase 2: round-1-proven per-edge logic, lane = channel ----
    for (int t = 0; t < 16; ++t) {
      const int ej = e0 + t;
      const int sN = src[ej], dN = dst[ej];
      const float x = xs[(wid << 4) + t][lane] + bb +
                      B1h[(size_t)sN * D + lane] + B2h[(size_t)dN * D + lane];
      const float a2v = A2h[(size_t)sN * D + lane];
      const float mu = wave_sum(x) * (1.f / 64.f);
      const float dx = x - mu;
      const float var = wave_sum(dx * dx) * (1.f / 64.f);
      float y = dx * rsqrtf(var + LN_EPS) * gl + bl;
      y = fmaxf(y, 0.f) + e[(size_t)ej * D + lane];
      eout[(size_t)ej * D + lane] = y;
      const float sg = 1.f / (1.f + __expf(-y));
      atomicAdd(&ssh[(size_t)dN * D + lane], a2v * sg);
      atomicAdd(&ss[(size_t)dN * D + lane], sg);
    }
  }
}

// h_out = relu(LN(A1h + ssh/(ss+eps))) + h
__global__ __launch_bounds__(256) void node_out_kernel(
    const float* __restrict__ h, const float* __restrict__ A1h,
    const float* __restrict__ ssh, const float* __restrict__ ss,
    const float* __restrict__ g, const float* __restrict__ bta,
    float* __restrict__ hout, int n) {
  const int lane = threadIdx.x & 63;
  const int wave = blockIdx.x * 4 + (threadIdx.x >> 6);
  const int nw = gridDim.x * 4;
  const float gl = g[lane], bl = bta[lane];
  for (int n0 = wave; n0 < n; n0 += nw) {
    const size_t base = (size_t)n0 * D;
    const float x =
        A1h[base + lane] + ssh[base + lane] / (ss[base + lane] + DIV_EPS);
    const float mu = wave_sum(x) * (1.f / 64.f);
    const float dx = x - mu;
    const float var = wave_sum(dx * dx) * (1.f / 64.f);
    float y = dx * rsqrtf(var + LN_EPS) * gl + bl;
    y = fmaxf(y, 0.f) + h[base + lane];
    hout[base + lane] = y;
  }
}

extern "C" void kernel_launch(void* const* d_in, const int* in_sizes, int n_in,
                              void* d_out, int out_size, void* d_ws,
                              size_t ws_size, hipStream_t stream) {
  const float* h = (const float*)d_in[0];
  const float* e = (const float*)d_in[1];
  const int* src = (const int*)d_in[2];
  const int* dst = (const int*)d_in[3];
  const float* A1w = (const float*)d_in[4];
  const float* A1b = (const float*)d_in[5];
  const float* A2w = (const float*)d_in[6];
  const float* A2b = (const float*)d_in[7];
  const float* B1w = (const float*)d_in[8];
  const float* B1b = (const float*)d_in[9];
  const float* B2w = (const float*)d_in[10];
  const float* B2b = (const float*)d_in[11];
  const float* B3w = (const float*)d_in[12];
  const float* B3b = (const float*)d_in[13];
  const float* ln_e_g = (const float*)d_in[14];
  const float* ln_e_b = (const float*)d_in[15];
  const float* ln_h_g = (const float*)d_in[16];
  const float* ln_h_b = (const float*)d_in[17];

  const int N = in_sizes[0] / D;  // 100000
  const int E = in_sizes[1] / D;  // 1000000

  float* ws = (float*)d_ws;
  float* A1h = ws;
  float* A2h = ws + (size_t)N * D;
  float* B1h = ws + 2 * (size_t)N * D;
  float* B2h = ws + 3 * (size_t)N * D;
  float* ssh = ws + 4 * (size_t)N * D;
  float* ss = ws + 5 * (size_t)N * D;

  float* hout = (float*)d_out;
  float* eout = (float*)d_out + (size_t)N * D;

  hipMemsetAsync(ssh, 0, 2 * (size_t)N * D * sizeof(float), stream);

  // NOTE: mat slots swapped vs round 2 — B1/B2 in slots 0/1, A1/A2 in 2/3.
  // If a slot-2/3-specific bug exists, the failure will move to output 0.
  node_proj_mfma<<<1563, 256, 0, stream>>>(h, B1w, B1b, B2w, B2b, A1w, A1b,
                                           A2w, A2b, B1h, B2h, A1h, A2h, N);
  edge_mfma2<<<4096, 256, 0, stream>>>(e, src, dst, B1h, B2h, A2h, B3w, B3b,
                                       ln_e_g, ln_e_b, eout, ssh, ss, E);
  node_out_kernel<<<1024, 256, 0, stream>>>(h, A1h, ssh, ss, ln_h_g, ln_h_b,
                                            hout, N);
}